// Round 12
// baseline (172.964 us; speedup 1.0000x reference)
//
#include <hip/hip_runtime.h>
#include <hip/hip_bf16.h>

// Problem dims (fixed by reference)
#define BATCH 128
#define PIX   196
#define EDIM  2048
#define DDIM  512
#define ADIM  512
#define MTOT  (BATCH*PIX)   // 25088
#define BK    64
#define NKT   (EDIM/BK)     // 32 K-tiles
#define BM    256
#define NSLC  2             // N split: 2 slices of 256

typedef __attribute__((ext_vector_type(8))) short short8;
typedef __attribute__((ext_vector_type(4))) float f32x4;

__device__ __forceinline__ unsigned short f2bf(float f) {
    union { float f; unsigned int u; } c; c.f = f;
    unsigned int u = c.u;
    u += 0x7fffu + ((u >> 16) & 1u);   // round-to-nearest-even
    return (unsigned short)(u >> 16);
}

// HW cvt (v_cvt_pk_bf16_f32, RNE — matches f2bf; proven r7/r8 same absmax)
__device__ __forceinline__ short8 cvt8(float4 a, float4 b) {
    short8 v;
    v[0] = (short)__bfloat16_as_ushort(__float2bfloat16(a.x));
    v[1] = (short)__bfloat16_as_ushort(__float2bfloat16(a.y));
    v[2] = (short)__bfloat16_as_ushort(__float2bfloat16(a.z));
    v[3] = (short)__bfloat16_as_ushort(__float2bfloat16(a.w));
    v[4] = (short)__bfloat16_as_ushort(__float2bfloat16(b.x));
    v[5] = (short)__bfloat16_as_ushort(__float2bfloat16(b.y));
    v[6] = (short)__bfloat16_as_ushort(__float2bfloat16(b.z));
    v[7] = (short)__bfloat16_as_ushort(__float2bfloat16(b.w));
    return v;
}

#define GLOAD16(gp, lp) __builtin_amdgcn_global_load_lds( \
    (const __attribute__((address_space(1))) void*)(gp),  \
    (__attribute__((address_space(3))) void*)(lp), 16, 0, 0)

#define MFMA16(a, b, c) __builtin_amdgcn_mfma_f32_16x16x32_bf16(a, b, c, 0, 0, 0)

// ---------------------------------------------------------------------------
// Kernel 0: pack W_enc [K=2048][A=512] fp32 into per-(kt,ns) 32KB images, bf16.
// Image (kt,ns), 16B slot c (c=0..2047): chunk=c>>6, l=c&63;
//   wn=chunk>>3, j=(chunk>>1)&3, ks=chunk&1;
//   holds bf16 of W_enc[kt*64 + ks*32 + (l>>4)*8 + d][ns*256 + wn*64 + j*16 + (l&15)]
// gemm slurps images linearly; frag read chunk at chunk*1024 + lane*16.
// ---------------------------------------------------------------------------
__global__ __launch_bounds__(256) void pack_wenc(const float* __restrict__ Wenc,
                                                 unsigned short* __restrict__ WTp) {
    __shared__ float f[64 * 256];   // 64 KB: rows k=kt*64..+63, cols ns*256..+255
    const int kt = blockIdx.x >> 1;
    const int ns = blockIdx.x & 1;
    const int tid = threadIdx.x;
    #pragma unroll
    for (int i = 0; i < 16; ++i) {
        int idx  = tid + i * 256;          // float4 index
        int row  = idx >> 6;               // 0..63
        int col4 = idx & 63;               // 0..63 (float4 cols)
        float4 v = *(const float4*)&Wenc[(size_t)(kt * 64 + row) * ADIM
                                         + ns * 256 + col4 * 4];
        *(float4*)&f[row * 256 + col4 * 4] = v;
    }
    __syncthreads();
    #pragma unroll
    for (int cc = 0; cc < 8; ++cc) {
        int c = tid + cc * 256;            // 0..2047
        int chunk = c >> 6, l = c & 63;
        int wn = chunk >> 3, j = (chunk >> 1) & 3, ks = chunk & 1;
        int n_local = wn * 64 + j * 16 + (l & 15);
        int k0 = ks * 32 + (l >> 4) * 8;
        short8 v;
        #pragma unroll
        for (int d = 0; d < 8; ++d)
            v[d] = (short)f2bf(f[(k0 + d) * 256 + n_local]);
        *(short8*)(WTp + ((size_t)(kt * 2 + ns) * 2048 + c) * 8) = v;
    }
}

// ---------------------------------------------------------------------------
// Kernel 1: bias[b][a] = sum_d dec[b][d]*Wdec[d][a] + b_dec[a] + b_enc[a]
// ---------------------------------------------------------------------------
__global__ __launch_bounds__(256) void bias_kernel(const float* __restrict__ dec,
                                                   const float* __restrict__ Wdec,
                                                   const float* __restrict__ b_enc,
                                                   const float* __restrict__ b_dec,
                                                   float* __restrict__ bias) {
    __shared__ float ds[4 * DDIM];
    const int b0 = blockIdx.x * 4;
    for (int i = threadIdx.x; i < 4 * DDIM; i += 256)
        ds[i] = dec[(size_t)b0 * DDIM + i];
    __syncthreads();
    const int a0 = threadIdx.x * 2;
    float acc0[4] = {0.f, 0.f, 0.f, 0.f};
    float acc1[4] = {0.f, 0.f, 0.f, 0.f};
    for (int d = 0; d < DDIM; d++) {
        float2 w = *(const float2*)&Wdec[(size_t)d * ADIM + a0];
        #pragma unroll
        for (int bi = 0; bi < 4; bi++) {
            float dv = ds[bi * DDIM + d];
            acc0[bi] += dv * w.x;
            acc1[bi] += dv * w.y;
        }
    }
    float be0 = b_enc[a0] + b_dec[a0];
    float be1 = b_enc[a0 + 1] + b_dec[a0 + 1];
    #pragma unroll
    for (int bi = 0; bi < 4; bi++) {
        bias[(size_t)(b0 + bi) * ADIM + a0]     = acc0[bi] + be0;
        bias[(size_t)(b0 + bi) * ADIM + a0 + 1] = acc1[bi] + be1;
    }
}

// ---------------------------------------------------------------------------
// Kernel 2: fused att1 GEMM + relu + dot(W_full) -> att_part[ns][m]
// 256M x 256N x 64K tiles, 196 blocks (98 x 2 slices, XCD twin-swizzle),
// 512 thr / 8 waves (2M x 4N), wave tile 128x64, acc[8][4] -> 64 MFMA/wave
// per barrier period (4x round-11's 16: sync amortization is the lever).
// Double-buffered LDS (128 KB), ONE barrier per K-tile, counted vmcnt:
//   issue B(kt+1) [4 gload] -> cvt A(kt+1) [implicit vmcnt(4)] -> issue
//   A(kt+2) [8 loads] -> ds_write A(kt+1) -> ds_reads+64 MFMA -> vmcnt(8)
//   retires B(kt+1), keeps A(kt+2) in flight -> barrier.
// No setprio (harmful on lockstep GEMM, m190).
// ---------------------------------------------------------------------------
__global__ __launch_bounds__(512, 2) void gemm_att(const float* __restrict__ enc,
                                                   const unsigned short* __restrict__ WTp,
                                                   const float* __restrict__ bias,
                                                   const float* __restrict__ Wfull,
                                                   float* __restrict__ att_part) {
    __shared__ __align__(16) char ldsA[2][32768];
    __shared__ __align__(16) char ldsB[2][32768];

    const int tid  = threadIdx.x;
    const int lane = tid & 63;
    const int wid  = tid >> 6;          // 0..7
    const int wm   = wid >> 2;          // 0..1 (M half: 128 rows)
    const int wn   = wid & 3;           // 0..3 (N quarter: 64 cols)
    const int cif  = lane & 15;
    const int rgrp = lane >> 4;

    // XCD swizzle (bijective for 196): twins (g, ns=0/1) 8 slots apart.
    const int raw = blockIdx.x;
    int g, ns;
    if (raw < 192) { g = (raw >> 4) * 8 + (raw & 7); ns = (raw >> 3) & 1; }
    else           { int r2 = raw - 192; g = 96 + (r2 >> 1); ns = r2 & 1; }
    const int m0 = g * BM;

    // A: thread t -> row r=t>>1, k-half h=t&1 (32 floats per K-tile).
    const int r = tid >> 1, h = tid & 1;
    const float* pA = enc + (size_t)(m0 + r) * EDIM + h * 32;
    // ds_write chunk base: chunk = (r>>7)*16 + ((r>>4)&7)*2 + h; slot q*16+(r&15)
    const unsigned aWoff = (unsigned)(((r >> 7) * 16 + ((r >> 4) & 7) * 2 + h) * 1024
                                      + (r & 15) * 16);

    // B: wave wid copies image bytes [wid*4096, +4096) (4 x 1KB gload16).
    const char* pB = (const char*)WTp + (size_t)ns * 32768
                   + (size_t)wid * 4096 + (size_t)lane * 16;   // +kt*65536
    const unsigned bgOff = (unsigned)(wid * 4096);

    f32x4 acc[8][4] = {};
    float4 rg[8];   // A(kt+1) staging regs (1-deep)

    // ---- prologue ----
    {
        #pragma unroll
        for (int c = 0; c < 4; ++c)
            GLOAD16(pB + c * 1024, ldsB[0] + bgOff + c * 1024);
        float4 t[8];
        #pragma unroll
        for (int p = 0; p < 8; ++p) t[p] = *(const float4*)(pA + p * 4);       // A(0)
        #pragma unroll
        for (int p = 0; p < 8; ++p) rg[p] = *(const float4*)(pA + BK + p * 4); // A(1)
        #pragma unroll
        for (int q = 0; q < 4; ++q)
            *(short8*)(ldsA[0] + aWoff + q * 256) = cvt8(t[2 * q], t[2 * q + 1]);
        asm volatile("s_waitcnt vmcnt(8) lgkmcnt(0)" ::: "memory");  // B(0)+A(0) done
        __builtin_amdgcn_s_barrier();
    }

    // ---- main loop: kt = 0 .. NKT-3 (30 iters) ----
    for (int kt = 0; kt < NKT - 2; ++kt) {
        char* aR = ldsA[kt & 1];
        char* aW = ldsA[(kt + 1) & 1];
        char* bR = ldsB[kt & 1];
        char* bW = ldsB[(kt + 1) & 1];
        // 1. issue B(kt+1) (oldest vm group this iter)
        const char* ps = pB + (size_t)(kt + 1) * 65536;
        #pragma unroll
        for (int c = 0; c < 4; ++c)
            GLOAD16(ps + c * 1024, bW + bgOff + c * 1024);
        // 2. cvt A(kt+1) (implicit counted vmcnt(4)) -> s8
        short8 s8[4];
        #pragma unroll
        for (int q = 0; q < 4; ++q) s8[q] = cvt8(rg[2 * q], rg[2 * q + 1]);
        // 3. issue A(kt+2) reg loads (newest vm group; in flight over barrier)
        {
            const float* pa = pA + (size_t)(kt + 2) * BK;
            #pragma unroll
            for (int p = 0; p < 8; ++p) rg[p] = *(const float4*)(pa + p * 4);
        }
        // 4. ds_write A(kt+1)
        #pragma unroll
        for (int q = 0; q < 4; ++q)
            *(short8*)(aW + aWoff + q * 256) = s8[q];
        // 5-7. ds_read frags + 64 MFMA (compiler schedules counted lgkmcnt)
        #pragma unroll
        for (int ks = 0; ks < 2; ++ks) {
            short8 a[8], b[4];
            #pragma unroll
            for (int i = 0; i < 8; ++i)
                a[i] = *(const short8*)(aR + (wm * 16 + i * 2 + ks) * 1024 + lane * 16);
            #pragma unroll
            for (int j = 0; j < 4; ++j)
                b[j] = *(const short8*)(bR + (wn * 8 + j * 2 + ks) * 1024 + lane * 16);
            #pragma unroll
            for (int i = 0; i < 8; ++i)
                #pragma unroll
                for (int j = 0; j < 4; ++j)
                    acc[i][j] = MFMA16(a[i], b[j], acc[i][j]);
        }
        // 8. retire B(kt+1) (keep A(kt+2)'s 8 in flight), publish
        asm volatile("s_waitcnt vmcnt(8) lgkmcnt(0)" ::: "memory");
        __builtin_amdgcn_s_barrier();
    }

    // ---- peeled kt = NKT-2: stage A(NKT-1), B(NKT-1); no A(NKT) issue ----
    {
        const int kt = NKT - 2;
        char* aR = ldsA[kt & 1];
        char* aW = ldsA[(kt + 1) & 1];
        char* bR = ldsB[kt & 1];
        char* bW = ldsB[(kt + 1) & 1];
        const char* ps = pB + (size_t)(kt + 1) * 65536;
        #pragma unroll
        for (int c = 0; c < 4; ++c)
            GLOAD16(ps + c * 1024, bW + bgOff + c * 1024);
        short8 s8[4];
        #pragma unroll
        for (int q = 0; q < 4; ++q) s8[q] = cvt8(rg[2 * q], rg[2 * q + 1]);
        #pragma unroll
        for (int q = 0; q < 4; ++q)
            *(short8*)(aW + aWoff + q * 256) = s8[q];
        #pragma unroll
        for (int ks = 0; ks < 2; ++ks) {
            short8 a[8], b[4];
            #pragma unroll
            for (int i = 0; i < 8; ++i)
                a[i] = *(const short8*)(aR + (wm * 16 + i * 2 + ks) * 1024 + lane * 16);
            #pragma unroll
            for (int j = 0; j < 4; ++j)
                b[j] = *(const short8*)(bR + (wn * 8 + j * 2 + ks) * 1024 + lane * 16);
            #pragma unroll
            for (int i = 0; i < 8; ++i)
                #pragma unroll
                for (int j = 0; j < 4; ++j)
                    acc[i][j] = MFMA16(a[i], b[j], acc[i][j]);
        }
        asm volatile("s_waitcnt vmcnt(0) lgkmcnt(0)" ::: "memory");
        __builtin_amdgcn_s_barrier();
    }
    // ---- peeled kt = NKT-1: compute only ----
    {
        const int kt = NKT - 1;
        char* aR = ldsA[kt & 1];
        char* bR = ldsB[kt & 1];
        #pragma unroll
        for (int ks = 0; ks < 2; ++ks) {
            short8 a[8], b[4];
            #pragma unroll
            for (int i = 0; i < 8; ++i)
                a[i] = *(const short8*)(aR + (wm * 16 + i * 2 + ks) * 1024 + lane * 16);
            #pragma unroll
            for (int j = 0; j < 4; ++j)
                b[j] = *(const short8*)(bR + (wn * 8 + j * 2 + ks) * 1024 + lane * 16);
            #pragma unroll
            for (int i = 0; i < 8; ++i)
                #pragma unroll
                for (int j = 0; j < 4; ++j)
                    acc[i][j] = MFMA16(a[i], b[j], acc[i][j]);
        }
    }
    __syncthreads();   // all frag reads done before aliasing ldsA as red

    // ---- epilogue: relu(acc + bias) . Wfull over this slice's 256 cols ----
    float* red = (float*)ldsA;   // [4][256] f32 = 4 KB
    const int bf = m0 / PIX;     // 256 rows can span up to 3 batches
    const int t1 = (bf + 1) * PIX;
    const int t2 = (bf + 2) * PIX;
    const int b1 = (bf + 1 < BATCH) ? bf + 1 : BATCH - 1;
    const int b2 = (bf + 2 < BATCH) ? bf + 2 : BATCH - 1;
    float wf[4], bs0[4], bs1[4], bs2[4];
    #pragma unroll
    for (int j = 0; j < 4; ++j) {
        int aj = ns * 256 + wn * 64 + j * 16 + cif;
        wf[j]  = Wfull[aj];
        bs0[j] = bias[(size_t)bf * ADIM + aj];
        bs1[j] = bias[(size_t)b1 * ADIM + aj];
        bs2[j] = bias[(size_t)b2 * ADIM + aj];
    }
    #pragma unroll
    for (int i = 0; i < 8; ++i) {
        #pragma unroll
        for (int rr = 0; rr < 4; ++rr) {
            int ml = wm * 128 + i * 16 + rgrp * 4 + rr;
            int m  = m0 + ml;
            float s = 0.f;
            #pragma unroll
            for (int j = 0; j < 4; ++j) {
                float bj = (m >= t2) ? bs2[j] : ((m >= t1) ? bs1[j] : bs0[j]);
                float v = acc[i][j][rr] + bj;
                s += fmaxf(v, 0.f) * wf[j];
            }
            s += __shfl_xor(s, 1);
            s += __shfl_xor(s, 2);
            s += __shfl_xor(s, 4);
            s += __shfl_xor(s, 8);
            if (cif == 0) red[wn * 256 + ml] = s;
        }
    }
    __syncthreads();
    if (tid < BM)
        att_part[(size_t)ns * MTOT + m0 + tid] =
            red[tid] + red[256 + tid] + red[512 + tid] + red[768 + tid];
}

// ---------------------------------------------------------------------------
// Kernel 3: softmax over p; att = sum of 2 N-slice partials (b_full cancels)
// ---------------------------------------------------------------------------
__global__ __launch_bounds__(256) void softmax_kernel(const float* __restrict__ att_part,
                                                      float* __restrict__ alpha) {
    const int b = blockIdx.x;
    const int tid = threadIdx.x;
    const int lane = tid & 63, wid = tid >> 6;
    __shared__ float wred[4];

    float x = -1e30f;
    if (tid < PIX) {
        size_t m = (size_t)b * PIX + tid;
        x = att_part[m] + att_part[MTOT + m];
    }
    float mx = x;
    #pragma unroll
    for (int off = 32; off >= 1; off >>= 1) mx = fmaxf(mx, __shfl_xor(mx, off));
    if (lane == 0) wred[wid] = mx;
    __syncthreads();
    float gm = fmaxf(fmaxf(wred[0], wred[1]), fmaxf(wred[2], wred[3]));
    __syncthreads();

    float e = (tid < PIX) ? __expf(x - gm) : 0.f;
    float s = e;
    #pragma unroll
    for (int off = 32; off >= 1; off >>= 1) s += __shfl_xor(s, off);
    if (lane == 0) wred[wid] = s;
    __syncthreads();
    float gs = wred[0] + wred[1] + wred[2] + wred[3];

    if (tid < PIX) alpha[(size_t)b * PIX + tid] = e / gs;
}

// ---------------------------------------------------------------------------
// Kernel 4: out[b][e] = sum_p enc[b][p][e] * alpha[b][p]
// ---------------------------------------------------------------------------
__global__ __launch_bounds__(128) void weighted_kernel(const float* __restrict__ enc,
                                                       const float* __restrict__ alpha,
                                                       float* __restrict__ out) {
    const int b = blockIdx.x >> 2;
    const int q = blockIdx.x & 3;
    const int tid = threadIdx.x;
    __shared__ float al[PIX];
    for (int i = tid; i < PIX; i += 128) al[i] = alpha[(size_t)b * PIX + i];
    __syncthreads();

    const int e = q * 512 + tid * 4;
    const float4* src = (const float4*)(enc + (size_t)b * PIX * EDIM + e);
    float ax = 0.f, ay = 0.f, az = 0.f, aw = 0.f;
    #pragma unroll 4
    for (int p = 0; p < PIX; p++) {
        float av = al[p];
        float4 v = src[(size_t)p * (EDIM / 4)];
        ax += av * v.x; ay += av * v.y; az += av * v.z; aw += av * v.w;
    }
    float4 o; o.x = ax; o.y = ay; o.z = az; o.w = aw;
    *(float4*)&out[(size_t)b * EDIM + e] = o;
}

// ---------------------------------------------------------------------------
extern "C" void kernel_launch(void* const* d_in, const int* in_sizes, int n_in,
                              void* d_out, int out_size, void* d_ws, size_t ws_size,
                              hipStream_t stream) {
    const float* enc   = (const float*)d_in[0];   // [128,196,2048]
    const float* dec   = (const float*)d_in[1];   // [128,512]
    const float* Wenc  = (const float*)d_in[2];   // [2048,512]
    const float* benc  = (const float*)d_in[3];   // [512]
    const float* Wdec  = (const float*)d_in[4];   // [512,512]
    const float* bdec  = (const float*)d_in[5];   // [512]
    const float* Wfull = (const float*)d_in[6];   // [512]
    // d_in[7] = b_full: constant shift, cancels in softmax

    float* out_awe   = (float*)d_out;                       // [128,2048]
    float* out_alpha = (float*)d_out + BATCH * EDIM;        // [128,196]

    char* ws = (char*)d_ws;
    unsigned short* WTp = (unsigned short*)ws;                      // 2 MB packed images
    float* bias = (float*)(ws + (size_t)ADIM * EDIM * 2);           // 256 KB [128][512]
    float* att_part = (float*)(ws + (size_t)ADIM * EDIM * 2
                             + (size_t)BATCH * ADIM * 4);           // 2 x 100 KB

    pack_wenc<<<NKT * 2, 256, 0, stream>>>(Wenc, WTp);
    bias_kernel<<<BATCH / 4, 256, 0, stream>>>(dec, Wdec, benc, bdec, bias);
    gemm_att<<<(MTOT / BM) * NSLC, 512, 0, stream>>>(enc, WTp, bias, Wfull, att_part);
    softmax_kernel<<<BATCH, 256, 0, stream>>>(att_part, out_alpha);
    weighted_kernel<<<BATCH * 4, 128, 0, stream>>>(enc, out_alpha, out_awe);
}